// Round 12
// baseline (944148.730 us; speedup 1.0000x reference)
//
#include <hip/hip_runtime.h>

#define F     4096
#define T     2048
#define NBLK  256
#define NTHR  1024
#define K     4      // ring/mirror slots; lockstep proofs hold for K>=2

// d_ws layout:
//   [0, 4096)                    : claim[8] words (64B apart) — relay election
//                                  (memset 0 each launch)
//   [4096, +K*F*4)               : global ring[K][4096] u32 {tag16<<16 | f16}
//   [4096+K*F*4, +8*K*F*4)       : mirror[8 XCD][K][4096] u32, same packing
// Ring/mirror are NOT memset: tags self-describing (0xAA poison tag = 0xAAAA
// = 43690, never equals a real tag in 1..2049).

typedef unsigned long long u64;
typedef unsigned int u32;
typedef unsigned short u16;

template <int CTRL>
__device__ __forceinline__ float dpp_add(float x) {
    int xi = __builtin_bit_cast(int, x);
    int yi = __builtin_amdgcn_update_dpp(0, xi, CTRL, 0xf, 0xf, false);
    return x + __builtin_bit_cast(float, yi);
}

// Full wave64 sum; total lands in lane 63. VALU-only.
__device__ __forceinline__ float wave_sum(float x) {
    x = dpp_add<0x111>(x); // row_shr:1
    x = dpp_add<0x112>(x); // row_shr:2
    x = dpp_add<0x114>(x); // row_shr:4
    x = dpp_add<0x118>(x); // row_shr:8
    x = dpp_add<0x142>(x); // row_bcast:15
    x = dpp_add<0x143>(x); // row_bcast:31
    return x;
}

#define PIN4(v) asm volatile("" : "+v"((v).x), "+v"((v).y), "+v"((v).z), "+v"((v).w))

__device__ __forceinline__ u64 cload_u64(const u64* p) {
    return __hip_atomic_load(p, __ATOMIC_RELAXED, __HIP_MEMORY_SCOPE_AGENT);
}
__device__ __forceinline__ void cstore_u32(u32* p, u32 v) {
    __hip_atomic_store(p, v, __ATOMIC_RELAXED, __HIP_MEMORY_SCOPE_AGENT);
}

// sc0 load: bypass (possibly stale) L1, hit this XCD's L2 — where the relay's
// plain mirror stores land. Must NOT use sc1 (would bypass L2 -> stale L3).
__device__ __forceinline__ uint4 load_sc0_u32x4(const u32* p) {
    uint4 r;
    asm volatile("global_load_dwordx4 %0, %1, off sc0\n\ts_waitcnt vmcnt(0)"
                 : "=v"(r) : "v"(p) : "memory");
    return r;
}

__device__ __forceinline__ float half_to_f(u32 bits) {
    return (float)__builtin_bit_cast(_Float16, (u16)(bits & 0xffffu));
}

__global__ __launch_bounds__(NTHR, 4) void rc_kernel(
    const float* __restrict__ x, const float* __restrict__ Wres,
    const float* __restrict__ wout, float* __restrict__ out,
    u32* __restrict__ claim, u32* __restrict__ ring,
    u32* __restrict__ mirror, u32 use_mirror)
{
    __shared__ __align__(16) float fl[F];     // staged feats vector (16 KB)
    __shared__ float red[2][16][4];           // double-buffered matvec partials
    __shared__ float redo[2][16];             // double-buffered readout partials
    __shared__ u32 s_role;

    const int tid  = threadIdx.x;
    const int b    = blockIdx.x;
    const int w    = tid >> 6;
    const int lane = tid & 63;
    const int wr   = w & 3;   // row-group (4 rows each)
    const int wk   = w >> 2;  // k-group (1024 k each)

    // ---- XCD id + relay election (one relay per XCD) ----
    u32 xcd_raw;
    asm volatile("s_getreg_b32 %0, hwreg(HW_REG_XCC_ID)" : "=s"(xcd_raw));
    const u32 xcd = xcd_raw & 7;
    if (tid == 0) {
        u32 r = 0;
        if (use_mirror)
            r = (__hip_atomic_fetch_add(&claim[xcd * 16], 1u,
                    __ATOMIC_RELAXED, __HIP_MEMORY_SCOPE_AGENT) == 0u) ? 1u : 0u;
        s_role = r;
    }

    // ---- persistent W_res fragment: 4 rows x 16 k = 64 fp32 regs/lane ----
    const int row0 = b * 16 + wr * 4;
    const int kofs = wk * 1024 + lane * 4;
    float4 wreg[4][4];
#pragma unroll
    for (int j = 0; j < 4; ++j) {
        const float* wp = Wres + (size_t)(row0 + j) * F + kofs;
#pragma unroll
        for (int i = 0; i < 4; ++i)
            wreg[j][i] = *(const float4*)(wp + i * 256);
    }
#pragma unroll
    for (int j = 0; j < 4; ++j) {
        PIN4(wreg[j][0]); PIN4(wreg[j][1]); PIN4(wreg[j][2]); PIN4(wreg[j][3]);
    }

    // ---- persistent w_out fragment (fused readout): 8 fp32 regs/lane ----
    const int rrow = b * 2 + (wr & 1);
    const int i0   = (wr >> 1) * 2;
    const float* wop = wout + (size_t)rrow * F + kofs + i0 * 256;
    float4 wo0 = *(const float4*)(wop);
    float4 wo1 = *(const float4*)(wop + 256);
    PIN4(wo0); PIN4(wo1);

    // ---- x prefetch for step 0 ----
    float xval = 0.f;
    if (tid < 16) xval = x[(size_t)(b * 16 + tid) * T + 0];

    __syncthreads();  // publish s_role
    const bool pollRing = (s_role != 0) || !use_mirror;
    const bool doMirror = (s_role != 0) && use_mirror;

    const int ep = w * 256 + lane * 4;  // this lane's chunk base (elements)

    for (int t = 0; t <= T; ++t) {
        // ---- 1. acquire feats_{t-1} and stage to LDS ----
        if (t > 0) {
            const int slot = (t - 1) & (K - 1);
            const u32 tag = (u32)t;
            float4 v;
            if (pollRing) {
                // relay (or fallback mode): coherent data-as-flag poll of ring
                const u32* rs = ring + (size_t)slot * F + ep;
                u64 p01 = cload_u64((const u64*)rs);
                u64 p23 = cload_u64((const u64*)(rs + 2));
                bool okA = (((u32)p01 >> 16) == tag) & (((u32)(p01 >> 32) >> 16) == tag);
                bool okB = (((u32)p23 >> 16) == tag) & (((u32)(p23 >> 32) >> 16) == tag);
                while (!__all(okA & okB)) {
                    __builtin_amdgcn_s_sleep(1);
                    if (!okA) {
                        p01 = cload_u64((const u64*)rs);
                        okA = (((u32)p01 >> 16) == tag) & (((u32)(p01 >> 32) >> 16) == tag);
                    }
                    if (!okB) {
                        p23 = cload_u64((const u64*)(rs + 2));
                        okB = (((u32)p23 >> 16) == tag) & (((u32)(p23 >> 32) >> 16) == tag);
                    }
                }
                if (doMirror) {
                    uint4 q;
                    q.x = (u32)p01; q.y = (u32)(p01 >> 32);
                    q.z = (u32)p23; q.w = (u32)(p23 >> 32);
                    // plain store -> dirty in THIS XCD's L2 -> visible to peers
                    *(uint4*)(mirror + ((size_t)xcd * K + slot) * F + ep) = q;
                }
                v.x = half_to_f((u32)p01); v.y = half_to_f((u32)(p01 >> 32));
                v.z = half_to_f((u32)p23); v.w = half_to_f((u32)(p23 >> 32));
            } else {
                // consumer: poll this XCD's mirror via sc0 (L1-bypass, L2-hit)
                const u32* ms = mirror + ((size_t)xcd * K + slot) * F + ep;
                uint4 q = load_sc0_u32x4(ms);
                bool ok = ((q.x >> 16) == tag) & ((q.y >> 16) == tag)
                        & ((q.z >> 16) == tag) & ((q.w >> 16) == tag);
                int spin = 0;
                while (!__all(ok)) {
                    __builtin_amdgcn_s_sleep(1);
                    if (!ok) {
                        if (++spin > 2048) {
                            // hang-proof escape: ground truth from the ring
                            const u32* rs = ring + (size_t)slot * F + ep;
                            u64 a = cload_u64((const u64*)rs);
                            u64 c = cload_u64((const u64*)(rs + 2));
                            q.x = (u32)a; q.y = (u32)(a >> 32);
                            q.z = (u32)c; q.w = (u32)(c >> 32);
                        } else {
                            q = load_sc0_u32x4(ms);
                        }
                        ok = ((q.x >> 16) == tag) & ((q.y >> 16) == tag)
                           & ((q.z >> 16) == tag) & ((q.w >> 16) == tag);
                    }
                }
                v.x = half_to_f(q.x); v.y = half_to_f(q.y);
                v.z = half_to_f(q.z); v.w = half_to_f(q.w);
            }
            *(float4*)&fl[ep] = v;
        } else {
            *(float4*)&fl[ep] = make_float4(0.f, 0.f, 0.f, 0.f);  // feats_{-1}=0
        }
        __syncthreads();  // (L) feats staged

        // ---- 2. matvec from LDS + fused readout partial ----
        float4 f0 = *(const float4*)&fl[kofs + 0 * 256];
        float4 f1 = *(const float4*)&fl[kofs + 1 * 256];
        float4 f2 = *(const float4*)&fl[kofs + 2 * 256];
        float4 f3 = *(const float4*)&fl[kofs + 3 * 256];

        float acc0 = 0.f, acc1 = 0.f, acc2 = 0.f, acc3 = 0.f;
#define DOT_STEP(i, fv) \
        acc0 += wreg[0][i].x * fv.x + wreg[0][i].y * fv.y + wreg[0][i].z * fv.z + wreg[0][i].w * fv.w; \
        acc1 += wreg[1][i].x * fv.x + wreg[1][i].y * fv.y + wreg[1][i].z * fv.z + wreg[1][i].w * fv.w; \
        acc2 += wreg[2][i].x * fv.x + wreg[2][i].y * fv.y + wreg[2][i].z * fv.z + wreg[2][i].w * fv.w; \
        acc3 += wreg[3][i].x * fv.x + wreg[3][i].y * fv.y + wreg[3][i].z * fv.z + wreg[3][i].w * fv.w;
        DOT_STEP(0, f0)
        DOT_STEP(1, f1)
        DOT_STEP(2, f2)
        DOT_STEP(3, f3)
#undef DOT_STEP

        float4 ra, rb;
        if (i0 == 0) { ra = f0; rb = f1; } else { ra = f2; rb = f3; }
        float p = wo0.x * ra.x + wo0.y * ra.y + wo0.z * ra.z + wo0.w * ra.w
                + wo1.x * rb.x + wo1.y * rb.y + wo1.z * rb.z + wo1.w * rb.w;

        // ---- 3. wave reduce, lane63 -> LDS (double-buffered by t&1) ----
        acc0 = wave_sum(acc0);
        acc1 = wave_sum(acc1);
        acc2 = wave_sum(acc2);
        acc3 = wave_sum(acc3);
        p    = wave_sum(p);
        const int pb = t & 1;
        if (lane == 63) {
            red[pb][w][0] = acc0; red[pb][w][1] = acc1;
            red[pb][w][2] = acc2; red[pb][w][3] = acc3;
            redo[pb][w] = p;
        }
        __syncthreads();  // (A)

        // ---- 4. wave 0: combine, clamp, publish packed pair (store = flag) ----
        if (w == 0 && t < T) {
            if (lane < 16) {
                const int r = lane, rw = r >> 2, rj = r & 3;
                float s = red[pb][rw][rj] + red[pb][rw + 4][rj]
                        + red[pb][rw + 8][rj] + red[pb][rw + 12][rj];
                s += xval;
                s = fminf(1.f, fmaxf(-1.f, s));
                u32 hb = (u32)__builtin_bit_cast(u16, (_Float16)s);
                u32 pk = ((u32)(t + 1) << 16) | hb;
                cstore_u32(ring + (size_t)(t & (K - 1)) * F + b * 16 + r, pk);
                const int tn = (t + 1 < T) ? (t + 1) : (T - 1);
                xval = x[(size_t)(b * 16 + lane) * T + tn];  // off critical path
            }
        }

        // ---- 5. out[:, t-1] store (wave 1; off the publish path) ----
        if (t > 0 && tid >= 64 && tid < 66) {
            const int r = tid - 64;
            float s = redo[pb][r]      + redo[pb][r + 2]  + redo[pb][r + 4]
                    + redo[pb][r + 6]  + redo[pb][r + 8]  + redo[pb][r + 10]
                    + redo[pb][r + 12] + redo[pb][r + 14];
            out[(size_t)(b * 2 + r) * T + (t - 1)] = s;
        }
        // Slot-reuse safety (K=4): a producer publishes step t only after all
        // blocks consumed t-2 (through its own consume of t-1); relays mirror
        // step t only after all producers published t, which implies everyone
        // consumed t-1. Oldest possibly-in-flight read when a slot is rewritten
        // is 2 steps back -> K>=2 suffices.
    }
}

extern "C" void kernel_launch(void* const* d_in, const int* in_sizes, int n_in,
                              void* d_out, int out_size, void* d_ws, size_t ws_size,
                              hipStream_t stream) {
    const float* x    = (const float*)d_in[0];
    const float* Wres = (const float*)d_in[1];
    const float* wout = (const float*)d_in[2];
    float* out        = (float*)d_out;

    u32* claim  = (u32*)d_ws;
    u32* ring   = (u32*)((char*)d_ws + 4096);
    u32* mirror = (u32*)((char*)d_ws + 4096 + (size_t)K * F * 4);

    const size_t need = 4096 + (size_t)K * F * 4 + (size_t)8 * K * F * 4;
    u32 use_mirror = (ws_size >= need) ? 1u : 0u;

    // zero the relay-claim words only; ring/mirror tags are self-describing
    (void)hipMemsetAsync(d_ws, 0, 4096, stream);

    void* args[] = { (void*)&x, (void*)&Wres, (void*)&wout, (void*)&out,
                     (void*)&claim, (void*)&ring, (void*)&mirror,
                     (void*)&use_mirror };
    (void)hipLaunchCooperativeKernel((const void*)rc_kernel, dim3(NBLK), dim3(NTHR),
                                     args, 0, stream);
}